// Round 2
// baseline (329.169 us; speedup 1.0000x reference)
//
#include <hip/hip_runtime.h>

#define DIM 64
#define NB 16
#define SEQ 2048

typedef __attribute__((ext_vector_type(8))) short bf16x8;   // 8 bf16 in 4 VGPRs
typedef __attribute__((ext_vector_type(4))) float f32x4;

// round-to-nearest-even fp32 -> bf16
__device__ __forceinline__ unsigned short f2bf(float f) {
    unsigned int u = __builtin_bit_cast(unsigned int, f);
    u = (u + 0x7fffu + ((u >> 16) & 1u)) >> 16;
    return (unsigned short)u;
}

// Load 8 consecutive fp32 and convert to a bf16x8 MFMA fragment.
__device__ __forceinline__ bf16x8 load_frag(const float* __restrict__ p) {
    f32x4 f0 = *reinterpret_cast<const f32x4*>(p);
    f32x4 f1 = *reinterpret_cast<const f32x4*>(p + 4);
    bf16x8 o;
    o[0] = (short)f2bf(f0[0]); o[1] = (short)f2bf(f0[1]);
    o[2] = (short)f2bf(f0[2]); o[3] = (short)f2bf(f0[3]);
    o[4] = (short)f2bf(f1[0]); o[5] = (short)f2bf(f1[1]);
    o[6] = (short)f2bf(f1[2]); o[7] = (short)f2bf(f1[3]);
    return o;
}

// Fused gather + GEMM: C[b] = (W[seq[b]] · W[seq[b]]^T) / 8.
// One block per 128x128 output tile; 4 waves, each wave a 32x128 strip.
// Fragment gather is per-lane direct from the fp32 weight table (the MFMA
// A/B layouts need 16 rows x 16B per fragment — exactly a row gather).
// Layouts (verified m89/m91):
//   A[m=lane&15][k=(lane>>4)*8+j], B[k=(lane>>4)*8+j][n=lane&15]
//   C: col=lane&15, row=(lane>>4)*4+reg (output symmetric -> swap-safe)
__global__ __launch_bounds__(256) void synergy_fused(
        const int* __restrict__ seq,
        const float* __restrict__ weight,
        float* __restrict__ out) {
    const int b    = blockIdx.z;
    const int n0   = blockIdx.x * 128;
    const int wave = threadIdx.x >> 6;
    const int lane = threadIdx.x & 63;
    const int m0   = blockIdx.y * 128 + wave * 32;
    const int r    = lane & 15;
    const int q    = lane >> 4;

    const int* sb = seq + b * SEQ;

    // Row indices for this lane's fragments (coalesced 16-wide int loads).
    int arow[2], brow[8];
#pragma unroll
    for (int mt = 0; mt < 2; ++mt) arow[mt] = sb[m0 + mt * 16 + r];
#pragma unroll
    for (int nt = 0; nt < 8; ++nt) brow[nt] = sb[n0 + nt * 16 + r];

    // A fragments: k-halves at fp32 offsets q*8 and 32+q*8 within the row.
    bf16x8 a[2][2];
#pragma unroll
    for (int mt = 0; mt < 2; ++mt) {
        const float* p = weight + (size_t)arow[mt] * DIM + q * 8;
        a[mt][0] = load_frag(p);
        a[mt][1] = load_frag(p + 32);
    }

    f32x4 acc[2][8];
    // Process B in two groups of 4 n-tiles to cap the live register set.
#pragma unroll
    for (int g = 0; g < 2; ++g) {
        bf16x8 bv[4][2];
#pragma unroll
        for (int t = 0; t < 4; ++t) {
            const float* p = weight + (size_t)brow[g * 4 + t] * DIM + q * 8;
            bv[t][0] = load_frag(p);
            bv[t][1] = load_frag(p + 32);
        }
#pragma unroll
        for (int mt = 0; mt < 2; ++mt)
#pragma unroll
            for (int t = 0; t < 4; ++t) {
                f32x4 c = {0.f, 0.f, 0.f, 0.f};
                c = __builtin_amdgcn_mfma_f32_16x16x32_bf16(a[mt][0], bv[t][0], c, 0, 0, 0);
                c = __builtin_amdgcn_mfma_f32_16x16x32_bf16(a[mt][1], bv[t][1], c, 0, 0, 0);
                acc[mt][g * 4 + t] = c;
            }
    }

    // Epilogue: scale by 1/sqrt(64), nontemporal store (bypass L2 allocate;
    // each 16-lane group covers a full aligned 64B segment).
#pragma unroll
    for (int mt = 0; mt < 2; ++mt)
#pragma unroll
        for (int reg = 0; reg < 4; ++reg) {
            int row = m0 + mt * 16 + q * 4 + reg;
            float* orow = out + ((size_t)b * SEQ + row) * SEQ + n0;
#pragma unroll
            for (int nt = 0; nt < 8; ++nt)
                __builtin_nontemporal_store(acc[mt][nt][reg] * 0.125f,
                                            orow + nt * 16 + r);
        }
}

extern "C" void kernel_launch(void* const* d_in, const int* in_sizes, int n_in,
                              void* d_out, int out_size, void* d_ws, size_t ws_size,
                              hipStream_t stream) {
    const int*   seq    = (const int*)d_in[0];     // [16,2048] int32
    const float* weight = (const float*)d_in[1];   // [32000,64] fp32
    float*       out    = (float*)d_out;           // [16,2048,2048] fp32
    (void)d_ws; (void)ws_size;

    synergy_fused<<<dim3(SEQ / 128, SEQ / 128, NB), dim3(256), 0, stream>>>(seq, weight, out);
}

// Round 3
// 287.693 us; speedup vs baseline: 1.1442x; 1.1442x over previous
//
#include <hip/hip_runtime.h>

#define DIM 64
#define NB 16
#define SEQ 2048

typedef __attribute__((ext_vector_type(8))) short bf16x8;   // 8 bf16 in 4 VGPRs
typedef __attribute__((ext_vector_type(4))) float f32x4;

// round-to-nearest-even fp32 -> bf16
__device__ __forceinline__ unsigned short f2bf(float f) {
    unsigned int u = __builtin_bit_cast(unsigned int, f);
    u = (u + 0x7fffu + ((u >> 16) & 1u)) >> 16;
    return (unsigned short)u;
}

// Gather weight rows per token and convert to bf16 ONCE (4 MiB compact table
// in d_ws -> fits per-XCD L2; the GEMM then reads it with high L2 hit rate).
// One thread per 8 elements: 16*2048 tokens * 8 chunks = 262144 threads.
__global__ __launch_bounds__(256) void gather_cvt(
        const int* __restrict__ seq,
        const float* __restrict__ weight,
        unsigned short* __restrict__ embs) {
    int tid = blockIdx.x * 256 + threadIdx.x;
    int token = tid >> 3;
    int c = (tid & 7) * 8;
    int row = seq[token];
    const float* src = weight + (size_t)row * DIM + c;
    unsigned short o[8];
#pragma unroll
    for (int j = 0; j < 8; ++j) o[j] = f2bf(src[j]);
    *reinterpret_cast<bf16x8*>(embs + (size_t)token * DIM + c) =
        *reinterpret_cast<bf16x8*>(o);
}

// Per batch: C = E * E^T / 8, M=N=2048, K=64 (single k-tile, no LDS).
// Block = 128x128 tile of C, 4 waves, each wave 32 rows x 128 cols.
// Fragment layouts (verified learn_hip m89/m91):
//   A[m=lane&15][k=(lane>>4)*8+j], B[k=(lane>>4)*8+j][n=lane&15]
//   C: col=lane&15, row=(lane>>4)*4+reg (output symmetric -> swap-safe)
__global__ __launch_bounds__(256) void synergy_gemm(
        const unsigned short* __restrict__ embs,
        float* __restrict__ out) {
    const int b    = blockIdx.z;
    const int n0   = blockIdx.x * 128;
    const int wave = threadIdx.x >> 6;
    const int lane = threadIdx.x & 63;
    const int m0   = blockIdx.y * 128 + wave * 32;
    const int r    = lane & 15;
    const int q    = lane >> 4;

    const unsigned short* eb = embs + (size_t)b * SEQ * DIM;

    bf16x8 a[2][2], bv[8][2];
#pragma unroll
    for (int mt = 0; mt < 2; ++mt) {
        const unsigned short* p = eb + (size_t)(m0 + mt * 16 + r) * DIM + q * 8;
        a[mt][0] = *reinterpret_cast<const bf16x8*>(p);
        a[mt][1] = *reinterpret_cast<const bf16x8*>(p + 32);
    }
#pragma unroll
    for (int nt = 0; nt < 8; ++nt) {
        const unsigned short* p = eb + (size_t)(n0 + nt * 16 + r) * DIM + q * 8;
        bv[nt][0] = *reinterpret_cast<const bf16x8*>(p);
        bv[nt][1] = *reinterpret_cast<const bf16x8*>(p + 32);
    }

    f32x4 acc[2][8];
#pragma unroll
    for (int mt = 0; mt < 2; ++mt)
#pragma unroll
        for (int nt = 0; nt < 8; ++nt) {
            f32x4 c = {0.f, 0.f, 0.f, 0.f};
            c = __builtin_amdgcn_mfma_f32_16x16x32_bf16(a[mt][0], bv[nt][0], c, 0, 0, 0);
            c = __builtin_amdgcn_mfma_f32_16x16x32_bf16(a[mt][1], bv[nt][1], c, 0, 0, 0);
            acc[mt][nt] = c;
        }

    // Epilogue: scale by 1/sqrt(64); NONTEMPORAL store (the only change vs R1):
    // the 256 MiB output stream bypasses L2 allocate so the 4 MiB embs table
    // stays L2-resident. Each 16-lane group writes a full aligned 64B line.
#pragma unroll
    for (int mt = 0; mt < 2; ++mt)
#pragma unroll
        for (int reg = 0; reg < 4; ++reg) {
            int row = m0 + mt * 16 + q * 4 + reg;
            float* orow = out + ((size_t)b * SEQ + row) * SEQ + n0;
#pragma unroll
            for (int nt = 0; nt < 8; ++nt)
                __builtin_nontemporal_store(acc[mt][nt][reg] * 0.125f,
                                            orow + nt * 16 + r);
        }
}

extern "C" void kernel_launch(void* const* d_in, const int* in_sizes, int n_in,
                              void* d_out, int out_size, void* d_ws, size_t ws_size,
                              hipStream_t stream) {
    const int*   seq    = (const int*)d_in[0];     // [16,2048] int32
    const float* weight = (const float*)d_in[1];   // [32000,64] fp32
    float*       out    = (float*)d_out;           // [16,2048,2048] fp32
    unsigned short* embs = (unsigned short*)d_ws;  // [16,2048,64] bf16 = 4 MiB

    gather_cvt<<<dim3(262144 / 256), dim3(256), 0, stream>>>(seq, weight, embs);
    synergy_gemm<<<dim3(SEQ / 128, SEQ / 128, NB), dim3(256), 0, stream>>>(embs, out);
}